// Round 6
// baseline (524.086 us; speedup 1.0000x reference)
//
#include <hip/hip_runtime.h>

#define NODES 50000
#define MP    50048          // NODES padded to multiple of 128
#define EDGES 800000
#define GRAPHS 500
#define DIN 128
#define HID 512

typedef short bf16x8 __attribute__((ext_vector_type(8)));
typedef float f32x4 __attribute__((ext_vector_type(4)));

__device__ inline float bl(unsigned u) { return __uint_as_float(u << 16); }
__device__ inline float bh(unsigned u) { return __uint_as_float(u & 0xffff0000u); }
__device__ inline unsigned short f2b(float f) {
    unsigned u = __float_as_uint(f);
    return (unsigned short)((u + 0x7fffu + ((u >> 16) & 1u)) >> 16);  // RNE
}

// ---------------- graph structure build ----------------

// fused: out-degree count (edges) + per-graph node count
__global__ void count_all(const int* __restrict__ row, const int* __restrict__ ngi,
                          int* __restrict__ deg, int* __restrict__ gcnt) {
    int i = blockIdx.x * 256 + threadIdx.x;
    if (i < EDGES) atomicAdd(&deg[row[i]], 1);
    if (i < NODES) atomicAdd(&gcnt[ngi[i]], 1);
}

// fused: exclusive scan of deg -> off, plus dinv = rsqrt(deg+1)
__global__ __launch_bounds__(1024) void scan_offsets(const int* __restrict__ deg,
                                                     int* __restrict__ off,
                                                     float* __restrict__ dinv, int N) {
    __shared__ int sums[1024];
    int tid = threadIdx.x;
    int chunk = (N + 1023) / 1024;
    int start = tid * chunk;
    int end = min(start + chunk, N);
    int s = 0;
    for (int i = start; i < end; ++i) s += deg[i];
    sums[tid] = s;
    __syncthreads();
    for (int o = 1; o < 1024; o <<= 1) {
        int v = (tid >= o) ? sums[tid - o] : 0;
        __syncthreads();
        sums[tid] += v;
        __syncthreads();
    }
    int run = sums[tid] - s;  // exclusive prefix
    for (int i = start; i < end; ++i) {
        int d = deg[i];
        off[i] = run;
        dinv[i] = rsqrtf((float)(d + 1));
        run += d;
    }
    if (tid == 1023) off[N] = sums[1023];
}

// CSR fill with packed payload: epk[e] = (bf16(dinv[col]) << 16) | col  (col < 65536)
__global__ void fill_csr(const int* __restrict__ row, const int* __restrict__ col,
                         const int* __restrict__ off, int* __restrict__ cursor,
                         const float* __restrict__ dinv, unsigned* __restrict__ epk, int E) {
    int e = blockIdx.x * 256 + threadIdx.x;
    if (e < E) {
        int r = row[e], c = col[e];
        int p = atomicAdd(&cursor[r], 1);
        epk[off[r] + p] = (((unsigned)f2b(dinv[c])) << 16) | (unsigned)c;
    }
}

__global__ __launch_bounds__(512) void scan_graph(const int* __restrict__ gcnt,
                                                  int* __restrict__ goff) {
    __shared__ int s[512];
    int t = threadIdx.x;
    s[t] = (t < GRAPHS) ? gcnt[t] : 0;
    __syncthreads();
    for (int o = 1; o < 512; o <<= 1) {
        int v = (t >= o) ? s[t - o] : 0;
        __syncthreads();
        s[t] += v;
        __syncthreads();
    }
    if (t == 0) goff[0] = 0;
    if (t < GRAPHS) goff[t + 1] = s[t];
}

// ---------------- fused prep: cvt x -> bf16, transpose W0/W1 -> bf16 ----------------

#define NA (NODES * DIN / 4)       // 1,600,000 float4 jobs
#define NB (DIN * HID)             // 65,536 W0T jobs
#define NC (HID * HID)             // 262,144 W1T jobs

__global__ void prep(const float* __restrict__ x, const float* __restrict__ W0,
                     const float* __restrict__ W1, unsigned short* __restrict__ XB,
                     unsigned short* __restrict__ W0T, unsigned short* __restrict__ W1T) {
    int i = blockIdx.x * 256 + threadIdx.x;
    if (i < NA) {
        float4 v = ((const float4*)x)[i];
        ushort4 o;
        o.x = f2b(v.x); o.y = f2b(v.y); o.z = f2b(v.z); o.w = f2b(v.w);
        ((ushort4*)XB)[i] = o;
        return;
    }
    int b = i - NA;
    if (b < NB) {  // W0 [128][512] -> W0T [512][128]
        int n = b & 511, k = b >> 9;
        W0T[n * DIN + k] = f2b(W0[k * HID + n]);
        return;
    }
    int c = b - NB;
    if (c < NC) {  // W1 [512][512] -> W1T [512][512]
        int n = c & 511, k = c >> 9;
        W1T[n * HID + k] = f2b(W1[k * HID + n]);
    }
}

// ---------------- L2-resident sliced aggregation ----------------
// Slice = 32 feats (64B = 4 uint4) -> 3.2MB per slice, fits 4MB XCD L2.
// Wave = 4 nodes x [4 edge-groups x 4 feat-lanes]. 1KB/wave gather (16 edges).
// MODE 0 (D=128, 4 slices):  slice = bid&3 (XCDs k, k+4 share slice k&3).
// MODE 1 (D=512, 16 slices): time-phased so XCD k serves slice 2k then 2k+1.
// epk supplies (col, bf16 dinv) in one 4B load; accumulators fp32.

__device__ inline void acc8(float* a, uint4 v, float d) {
    a[0] += bl(v.x) * d; a[1] += bh(v.x) * d;
    a[2] += bl(v.y) * d; a[3] += bh(v.y) * d;
    a[4] += bl(v.z) * d; a[5] += bh(v.z) * d;
    a[6] += bl(v.w) * d; a[7] += bh(v.w) * d;
}

template <int RS4, int MODE, bool EPI>  // RS4 = row stride in uint4 (D/8)
__global__ __launch_bounds__(256) void agg_g4(const unsigned short* __restrict__ Sp,
                                              const int* __restrict__ off,
                                              const unsigned* __restrict__ epk,
                                              const float* __restrict__ dinv,
                                              const float* __restrict__ bias,
                                              unsigned short* __restrict__ Op) {
    int slice, chunk;
    if (MODE == 0) {
        slice = blockIdx.x & 3; chunk = blockIdx.x >> 2;
    } else {
        const int xcd = blockIdx.x & 7;
        const int t = blockIdx.x >> 3;          // 0..6249
        const int ph = (t >= 3125) ? 1 : 0;
        chunk = t - ph * 3125;
        slice = xcd * 2 + ph;
    }
    const int l = threadIdx.x & 63;
    const int n = chunk * 16 + (threadIdx.x >> 6) * 4 + (l >> 4);   // 16 nodes/block
    const int g = (l >> 2) & 3;                 // edge group within node
    const int j = l & 3;                        // uint4 within 64B slice
    const uint4* H4 = (const uint4*)Sp;
    const unsigned fo = slice * 4 + j;
    const float dn = dinv[n];
    const int s = off[n], e = off[n + 1];
    float a[8] = {};
    if (g == 0) acc8(a, H4[(unsigned)n * RS4 + fo], dn);   // self loop
    for (int i = s + g; i < e; i += 4) {
        unsigned u = epk[i];
        acc8(a, H4[(u & 0xffffu) * RS4 + fo], bh(u));
    }
#pragma unroll
    for (int k = 0; k < 8; ++k) a[k] += __shfl_xor(a[k], 4);
#pragma unroll
    for (int k = 0; k < 8; ++k) a[k] += __shfl_xor(a[k], 8);
    if (g == 0) {
        float o0, o1, o2, o3, o4, o5, o6, o7;
        if constexpr (EPI) {
            const float4 b0 = ((const float4*)bias)[fo * 2];
            const float4 b1 = ((const float4*)bias)[fo * 2 + 1];
            o0 = fmaxf(a[0] * dn + b0.x, 0.f); o1 = fmaxf(a[1] * dn + b0.y, 0.f);
            o2 = fmaxf(a[2] * dn + b0.z, 0.f); o3 = fmaxf(a[3] * dn + b0.w, 0.f);
            o4 = fmaxf(a[4] * dn + b1.x, 0.f); o5 = fmaxf(a[5] * dn + b1.y, 0.f);
            o6 = fmaxf(a[6] * dn + b1.z, 0.f); o7 = fmaxf(a[7] * dn + b1.w, 0.f);
        } else {
            o0 = a[0] * dn; o1 = a[1] * dn; o2 = a[2] * dn; o3 = a[3] * dn;
            o4 = a[4] * dn; o5 = a[5] * dn; o6 = a[6] * dn; o7 = a[7] * dn;
        }
        uint4 ov;
        ov.x = (unsigned)f2b(o0) | ((unsigned)f2b(o1) << 16);
        ov.y = (unsigned)f2b(o2) | ((unsigned)f2b(o3) << 16);
        ov.z = (unsigned)f2b(o4) | ((unsigned)f2b(o5) << 16);
        ov.w = (unsigned)f2b(o6) | ((unsigned)f2b(o7) << 16);
        ((uint4*)Op)[(unsigned)n * RS4 + fo] = ov;
    }
}

// ---------------- bf16 MFMA GEMM: C[MP][512] = A[MP][K] @ W[K][512] ----------------
// 128x128 tile, BK=64, 4 waves; global_load_lds(16B) staging with XOR chunk
// swizzle. 1D grid + bijective XCD chunk-swizzle (N fastest within a chunk).

template <int K, bool EPI>
__global__ __launch_bounds__(256) void gemm_mfma(const unsigned short* __restrict__ A,
                                                 const unsigned short* __restrict__ BT,
                                                 const float* __restrict__ bias,
                                                 unsigned short* __restrict__ C) {
    __shared__ unsigned short As[128 * 64];
    __shared__ unsigned short Bs[128 * 64];
    const int nwg = gridDim.x;
    const int q = nwg >> 3, r = nwg & 7;
    const int x = blockIdx.x & 7, ii = blockIdx.x >> 3;
    const int swz = (x < r ? x * (q + 1) : r * (q + 1) + (x - r) * q) + ii;
    const int m0 = (swz >> 2) * 128;   // 4 N-tiles, fastest
    const int n0 = (swz & 3) * 128;

    const int t = threadIdx.x;
    const int w = t >> 6, l = t & 63;
    const int wr = w >> 1, wc = w & 1;
    f32x4 acc[4][4] = {};
    const int lr = l >> 3;                 // row within 8-row group
    const int swzc = (l & 7) ^ lr;         // pre-swizzled source chunk

    for (int k0 = 0; k0 < K; k0 += 64) {
#pragma unroll
        for (int c = 0; c < 4; ++c) {
            const int rg = (w * 4 + c) * 8;  // tile-local row-group base
            const unsigned short* ga = &A[(size_t)(m0 + rg + lr) * K + k0 + swzc * 8];
            const unsigned short* gb = &BT[(size_t)(n0 + rg + lr) * K + k0 + swzc * 8];
            __builtin_amdgcn_global_load_lds(
                (const __attribute__((address_space(1))) void*)ga,
                (__attribute__((address_space(3))) void*)&As[rg * 64], 16, 0, 0);
            __builtin_amdgcn_global_load_lds(
                (const __attribute__((address_space(1))) void*)gb,
                (__attribute__((address_space(3))) void*)&Bs[rg * 64], 16, 0, 0);
        }
        __syncthreads();
#pragma unroll
        for (int kk = 0; kk < 2; ++kk) {
            const int ch = (kk * 4 + (l >> 4)) ^ (l & 7);  // swizzled read chunk
            bf16x8 af[4], bg[4];
#pragma unroll
            for (int m = 0; m < 4; ++m)
                af[m] = *(const bf16x8*)&As[(wr * 64 + m * 16 + (l & 15)) * 64 + ch * 8];
#pragma unroll
            for (int n = 0; n < 4; ++n)
                bg[n] = *(const bf16x8*)&Bs[(wc * 64 + n * 16 + (l & 15)) * 64 + ch * 8];
#pragma unroll
            for (int m = 0; m < 4; ++m)
#pragma unroll
                for (int n = 0; n < 4; ++n)
                    acc[m][n] = __builtin_amdgcn_mfma_f32_16x16x32_bf16(af[m], bg[n], acc[m][n], 0, 0, 0);
        }
        __syncthreads();
    }
    const int ro = 4 * (l >> 4);
    const int co = l & 15;
#pragma unroll
    for (int m = 0; m < 4; ++m)
#pragma unroll
        for (int n = 0; n < 4; ++n) {
            int col = n0 + wc * 64 + n * 16 + co;
            float bv = EPI ? bias[col] : 0.f;
#pragma unroll
            for (int r = 0; r < 4; ++r) {
                int row = m0 + wr * 64 + m * 16 + ro + r;
                float v = acc[m][n][r];
                if (EPI) v = fmaxf(v + bv, 0.f);
                C[(size_t)row * HID + col] = f2b(v);
            }
        }
}

// ---------------- fused sum pooling + classifier ----------------

__global__ __launch_bounds__(64) void pool_logits(const unsigned short* __restrict__ H,
                                                  const int* __restrict__ goff,
                                                  const float* __restrict__ Wfc,
                                                  const float* __restrict__ bfc,
                                                  float* __restrict__ out) {
    int g = blockIdx.x, l = threadIdx.x;
    int s = goff[g], e = goff[g + 1];
    float a[8] = {};
    for (int n = s; n < e; ++n) {
        uint4 v = ((const uint4*)H)[(size_t)n * 64 + l];
        a[0] += bl(v.x); a[1] += bh(v.x); a[2] += bl(v.y); a[3] += bh(v.y);
        a[4] += bl(v.z); a[5] += bh(v.z); a[6] += bl(v.w); a[7] += bh(v.w);
    }
    float p0 = 0.f, p1 = 0.f;
#pragma unroll
    for (int k = 0; k < 8; ++k) {
        int f = l * 8 + k;
        p0 += a[k] * Wfc[f * 2 + 0];
        p1 += a[k] * Wfc[f * 2 + 1];
    }
#pragma unroll
    for (int o = 32; o > 0; o >>= 1) {
        p0 += __shfl_down(p0, o);
        p1 += __shfl_down(p1, o);
    }
    if (l == 0) {
        out[g * 2 + 0] = p0 + bfc[0];
        out[g * 2 + 1] = p1 + bfc[1];
    }
}

// ---------------- launch ----------------

extern "C" void kernel_launch(void* const* d_in, const int* in_sizes, int n_in,
                              void* d_out, int out_size, void* d_ws, size_t ws_size,
                              hipStream_t stream) {
    const float* x   = (const float*)d_in[0];
    const int*   ei  = (const int*)d_in[1];
    const int*   ngi = (const int*)d_in[2];
    const float* W0  = (const float*)d_in[3];
    const float* b0  = (const float*)d_in[4];
    const float* W1  = (const float*)d_in[5];
    const float* b1  = (const float*)d_in[6];
    const float* Wfc = (const float*)d_in[7];
    const float* bfc = (const float*)d_in[8];
    float* out = (float*)d_out;

    const int* row = ei;
    const int* col = ei + EDGES;

    char* ws = (char*)d_ws;
    size_t o = 0;
    auto alloc = [&](size_t bytes) {
        o = (o + 255) & ~(size_t)255;
        void* p = ws + o;
        o += bytes;
        return p;
    };
    unsigned short* XB  = (unsigned short*)alloc((size_t)NODES * DIN * 2);  // bf16 x
    unsigned short* XA  = (unsigned short*)alloc((size_t)MP * DIN * 2);     // agg(x)
    unsigned short* H   = (unsigned short*)alloc((size_t)MP * HID * 2);     // relu(XA@W0+b0), reused for h2
    unsigned short* G   = (unsigned short*)alloc((size_t)MP * HID * 2);     // H@W1
    unsigned short* W0T = (unsigned short*)alloc((size_t)HID * DIN * 2);
    unsigned short* W1T = (unsigned short*)alloc((size_t)HID * HID * 2);
    int*   ints  = (int*)alloc((size_t)(NODES + NODES + 512) * 4);  // deg|cursor|gcnt (one memset)
    int*   deg    = ints;
    int*   cursor = ints + NODES;
    int*   gcnt   = ints + 2 * NODES;
    float* dinv  = (float*)alloc((size_t)NODES * 4);
    int*   off   = (int*)alloc((size_t)(NODES + 1) * 4);
    unsigned* epk = (unsigned*)alloc((size_t)EDGES * 4);   // packed (dinv_bf16 | col)
    int*   goff  = (int*)alloc(512 * 4);

    hipMemsetAsync(ints, 0, (size_t)(2 * NODES + 512) * 4, stream);
    // pad rows of XA must be finite (GEMM0 reads all MP rows)
    hipMemsetAsync(XA + (size_t)NODES * DIN, 0, (size_t)(MP - NODES) * DIN * 2, stream);

    count_all<<<(EDGES + 255) / 256, 256, 0, stream>>>(row, ngi, deg, gcnt);
    scan_offsets<<<1, 1024, 0, stream>>>(deg, off, dinv, NODES);
    fill_csr<<<(EDGES + 255) / 256, 256, 0, stream>>>(row, col, off, cursor, dinv, epk, EDGES);
    scan_graph<<<1, 512, 0, stream>>>(gcnt, goff);
    prep<<<(NA + NB + NC + 255) / 256, 256, 0, stream>>>(x, W0, W1, XB, W0T, W1T);

    // layer 0 (agg commutes with linear): XA = agg(XB); H = relu(XA @ W0 + b0)
    agg_g4<DIN / 8, 0, false><<<3125 * 4, 256, 0, stream>>>(XB, off, epk, dinv, nullptr, XA);
    gemm_mfma<DIN, true><<<4 * (MP / 128), 256, 0, stream>>>(XA, W0T, b0, H);

    // layer 1: G = H @ W1 ; H = relu(agg(G) + b1), 16 L2-resident slices, phased per XCD
    gemm_mfma<HID, false><<<4 * (MP / 128), 256, 0, stream>>>(H, W1T, nullptr, G);
    agg_g4<HID / 8, 1, true><<<3125 * 16, 256, 0, stream>>>(G, off, epk, dinv, b1, H);

    // fused pooling + classifier
    pool_logits<<<GRAPHS, 64, 0, stream>>>(H, goff, Wfc, bfc, out);
}